// Round 1
// baseline (16701.680 us; speedup 1.0000x reference)
//
#include <hip/hip_runtime.h>
#include <math.h>

#define B_  32
#define T_  64
#define TW_ 32
#define EW_ 300
#define H_  512
#define E_  1024
#define HH_ 512
#define C_  7
#define N_  2048   // B*T

__device__ __forceinline__ float sigm(float x){ return 1.f/(1.f+expf(-x)); }

// ---------------------------------------------------------------------------
// Phase 1: one BiLSTM time-step. grid (16 m-tiles, 64 n-tiles, 2 dirs), 256 thr.
// Computes gates = x_t @ Wih.T + h @ Whh.T + b for a 32n x 32m tile (x4 gates),
// then the cell update. h ping-pongs between hb_in/hb_out (no in-place race).
// ---------------------------------------------------------------------------
__global__ void lstm_step(const float* __restrict__ xin,
                          const float* __restrict__ Wih_f, const float* __restrict__ Whh_f, const float* __restrict__ b_f,
                          const float* __restrict__ Wih_b, const float* __restrict__ Whh_b, const float* __restrict__ b_b,
                          const float* __restrict__ hb_in, float* __restrict__ hb_out,
                          float* __restrict__ cbuf, float* __restrict__ feats, int t)
{
  const int dir = blockIdx.z;
  const float* Wih  = dir ? Wih_b : Wih_f;
  const float* Whh  = dir ? Whh_b : Whh_f;
  const float* bias = dir ? b_b  : b_f;
  const int wt = dir ? (TW_-1-t) : t;
  const int m0 = blockIdx.x*32;
  const int n0 = blockIdx.y*32;
  float*       cb  = cbuf  + (size_t)dir*N_*H_;
  const float* hin = hb_in + (size_t)dir*N_*H_;

  __shared__ __align__(16) float As[32][32];    // [k][n]
  __shared__ __align__(16) float Ws[32][128];   // [k][m_local*4 + gate]

  const int tid = threadIdx.x;
  const int tjx = tid & 31;       // m_local
  const int tby = tid >> 5;       // n quad index (0..7)
  const int nl  = tid >> 3, kq = (tid & 7)*4;   // As staging
  const int jl  = tid >> 1, kh = (tid & 1)*16;  // Ws staging
  const int ml  = jl >> 2,  gg = jl & 3;

  float acc[4][4];
  #pragma unroll
  for(int i=0;i<4;i++){ acc[i][0]=0.f; acc[i][1]=0.f; acc[i][2]=0.f; acc[i][3]=0.f; }

  // ---- input part: K = 300 (10 chunks of 32, zero-padded) ----
  const float* xsrc = xin + ((size_t)(n0+nl)*TW_ + wt)*EW_;
  const float* wsrcx = Wih + (size_t)(gg*H_ + m0 + ml)*EW_;
  for(int kc=0; kc<10; ++kc){
    const int k0 = kc*32;
    #pragma unroll
    for(int j=0;j<4;j++){
      int k = k0+kq+j;
      As[kq+j][nl] = (k<EW_) ? xsrc[k] : 0.f;
    }
    #pragma unroll
    for(int j=0;j<16;j++){
      int k = k0+kh+j;
      Ws[kh+j][jl] = (k<EW_) ? wsrcx[k] : 0.f;
    }
    __syncthreads();
    #pragma unroll
    for(int k=0;k<32;k++){
      float4 a4 = *(const float4*)&As[k][tby*4];
      float4 w4 = *(const float4*)&Ws[k][tjx*4];
      acc[0][0]+=a4.x*w4.x; acc[0][1]+=a4.x*w4.y; acc[0][2]+=a4.x*w4.z; acc[0][3]+=a4.x*w4.w;
      acc[1][0]+=a4.y*w4.x; acc[1][1]+=a4.y*w4.y; acc[1][2]+=a4.y*w4.z; acc[1][3]+=a4.y*w4.w;
      acc[2][0]+=a4.z*w4.x; acc[2][1]+=a4.z*w4.y; acc[2][2]+=a4.z*w4.z; acc[2][3]+=a4.z*w4.w;
      acc[3][0]+=a4.w*w4.x; acc[3][1]+=a4.w*w4.y; acc[3][2]+=a4.w*w4.z; acc[3][3]+=a4.w*w4.w;
    }
    __syncthreads();
  }
  // ---- hidden part: K = 512 (16 chunks of 32) ----
  const float* hsrc = hin + (size_t)(n0+nl)*H_;
  const float* wsrch = Whh + (size_t)(gg*H_ + m0 + ml)*H_;
  for(int kc=0; kc<16; ++kc){
    const int k0 = kc*32;
    #pragma unroll
    for(int j=0;j<4;j++) As[kq+j][nl] = hsrc[k0+kq+j];
    #pragma unroll
    for(int j=0;j<16;j++) Ws[kh+j][jl] = wsrch[k0+kh+j];
    __syncthreads();
    #pragma unroll
    for(int k=0;k<32;k++){
      float4 a4 = *(const float4*)&As[k][tby*4];
      float4 w4 = *(const float4*)&Ws[k][tjx*4];
      acc[0][0]+=a4.x*w4.x; acc[0][1]+=a4.x*w4.y; acc[0][2]+=a4.x*w4.z; acc[0][3]+=a4.x*w4.w;
      acc[1][0]+=a4.y*w4.x; acc[1][1]+=a4.y*w4.y; acc[1][2]+=a4.y*w4.z; acc[1][3]+=a4.y*w4.w;
      acc[2][0]+=a4.z*w4.x; acc[2][1]+=a4.z*w4.y; acc[2][2]+=a4.z*w4.z; acc[2][3]+=a4.z*w4.w;
      acc[3][0]+=a4.w*w4.x; acc[3][1]+=a4.w*w4.y; acc[3][2]+=a4.w*w4.z; acc[3][3]+=a4.w*w4.w;
    }
    __syncthreads();
  }
  // ---- cell update (gate order i,f,g,o) ----
  const int m = m0 + tjx;
  const float bi = bias[m], bf = bias[H_+m], bg = bias[2*H_+m], bo = bias[3*H_+m];
  float* hout = hb_out + (size_t)dir*N_*H_;
  #pragma unroll
  for(int i=0;i<4;i++){
    const int n = n0 + tby*4 + i;
    float gi = acc[i][0] + bi;
    float gf = acc[i][1] + bf;
    float gc = acc[i][2] + bg;
    float go = acc[i][3] + bo;
    float c_old = cb[(size_t)n*H_ + m];
    float c2 = sigm(gf)*c_old + sigm(gi)*tanhf(gc);
    float h2 = sigm(go)*tanhf(c2);
    cb[(size_t)n*H_ + m] = c2;
    if(t == TW_-1) feats[(size_t)n*E_ + dir*H_ + m] = h2;
    else           hout[(size_t)n*H_ + m] = h2;
  }
}

// ---------------------------------------------------------------------------
// Phase 2: split-K partial GEMM for GRU gates / q.
// out partial[((z*KS+ks)*B + b)*ROWS + j] = sum_{k in chunk} X[b][k] * W[j][k]
// X = xA (+ xB elementwise, optional). wdirect=1 means W is [K][ROWS] (q case).
// grid (ROWS/128, KS, nz), 256 threads, tile 32b x 128j.
// ---------------------------------------------------------------------------
struct GArg {
  const float* xA; const float* xB;
  long ldA; long ldB;
  const float* W; int K; int wdirect;
};

__global__ void gemm_part(GArg a0, GArg a1, int ROWS, int KS, float* __restrict__ part)
{
  const GArg a = blockIdx.z ? a1 : a0;
  const int j0 = blockIdx.x*128;
  const int ks = blockIdx.y;
  const int Kc = a.K / KS;
  const int kbase = ks*Kc;

  __shared__ __align__(16) float Xs[32][32];
  __shared__ __align__(16) float Ws[32][128];

  const int tid = threadIdx.x;
  const int tjx = tid & 31, tby = tid >> 5;
  const int bl = tid >> 3, kq = (tid & 7)*4;
  const int jl = tid >> 1, kh = (tid & 1)*16;
  const int kl = tid >> 3, jq = (tid & 7)*16;

  float acc[4][4];
  #pragma unroll
  for(int i=0;i<4;i++){ acc[i][0]=0.f; acc[i][1]=0.f; acc[i][2]=0.f; acc[i][3]=0.f; }

  for(int kc=0; kc<Kc; kc+=32){
    const int k0 = kbase + kc;
    #pragma unroll
    for(int j=0;j<4;j++){
      float v = a.xA[(size_t)bl*a.ldA + k0+kq+j];
      if(a.xB) v += a.xB[(size_t)bl*a.ldB + k0+kq+j];
      Xs[kq+j][bl] = v;
    }
    if(!a.wdirect){
      const float* wr = a.W + (size_t)(j0+jl)*a.K + k0 + kh;
      #pragma unroll
      for(int j=0;j<16;j++) Ws[kh+j][jl] = wr[j];
    } else {
      const float* wr = a.W + (size_t)(k0+kl)*ROWS + j0 + jq;
      #pragma unroll
      for(int j=0;j<16;j++) Ws[kl][jq+j] = wr[j];
    }
    __syncthreads();
    #pragma unroll
    for(int k=0;k<32;k++){
      float4 x4 = *(const float4*)&Xs[k][tby*4];
      float4 w4 = *(const float4*)&Ws[k][tjx*4];
      acc[0][0]+=x4.x*w4.x; acc[0][1]+=x4.x*w4.y; acc[0][2]+=x4.x*w4.z; acc[0][3]+=x4.x*w4.w;
      acc[1][0]+=x4.y*w4.x; acc[1][1]+=x4.y*w4.y; acc[1][2]+=x4.y*w4.z; acc[1][3]+=x4.y*w4.w;
      acc[2][0]+=x4.z*w4.x; acc[2][1]+=x4.z*w4.y; acc[2][2]+=x4.z*w4.z; acc[2][3]+=x4.z*w4.w;
      acc[3][0]+=x4.w*w4.x; acc[3][1]+=x4.w*w4.y; acc[3][2]+=x4.w*w4.z; acc[3][3]+=x4.w*w4.w;
    }
    __syncthreads();
  }
  float* dst = part + (size_t)(blockIdx.z*KS + ks)*B_*ROWS;
  #pragma unroll
  for(int i=0;i<4;i++){
    const int b = tby*4 + i;
    float4 v = make_float4(acc[i][0],acc[i][1],acc[i][2],acc[i][3]);
    *(float4*)&dst[(size_t)b*ROWS + j0 + tjx*4] = v;
  }
}

// ---------------------------------------------------------------------------
// GRU combine: reduce split-K partials, add biases, apply GRU cell (r,z,n order)
// ---------------------------------------------------------------------------
__global__ void gru_combine(const float* __restrict__ part, int ROWS, int KS,
                            const float* __restrict__ bih, const float* __restrict__ bhh,
                            const float* __restrict__ hprev, long ldh,
                            float* __restrict__ hout, long ldo,
                            float* __restrict__ copy2, int J)
{
  const int idx = blockIdx.x*256 + threadIdx.x;
  if(idx >= B_*J) return;
  const int b = idx / J, e = idx - b*J;
  float ir=0.f, iz=0.f, in_=0.f, hr=0.f, hz=0.f, hn=0.f;
  for(int ks=0; ks<KS; ++ks){
    const float* p0 = part + (size_t)(ks*B_ + b)*ROWS;
    const float* p1 = part + (size_t)((KS+ks)*B_ + b)*ROWS;
    ir += p0[e]; iz += p0[J+e]; in_ += p0[2*J+e];
    hr += p1[e]; hz += p1[J+e]; hn  += p1[2*J+e];
  }
  ir += bih[e]; iz += bih[J+e]; in_ += bih[2*J+e];
  hr += bhh[e]; hz += bhh[J+e]; hn  += bhh[2*J+e];
  const float r = sigm(ir+hr);
  const float z = sigm(iz+hz);
  const float n = tanhf(in_ + r*hn);
  const float hp = hprev[(size_t)b*ldh + e];
  const float h2 = (1.f-z)*n + z*hp;
  hout[(size_t)b*ldo + e] = h2;
  if(copy2) copy2[(size_t)b*J + e] = h2;
}

// ---------------------------------------------------------------------------
// Attention: reduce q partials, scores over hist[0..i], wave softmax, context,
// write xc = x_i + context. grid 32 (one block per b), 256 threads.
// ---------------------------------------------------------------------------
__global__ void att_step(const float* __restrict__ qpart, int KS,
                         const float* __restrict__ hist,
                         const float* __restrict__ feats,
                         float* __restrict__ xc, int i)
{
  const int b = blockIdx.x, tid = threadIdx.x;
  __shared__ float qs[E_];
  __shared__ float sc[T_+1];
  for(int e=tid; e<E_; e+=256){
    float v = 0.f;
    for(int ks=0; ks<KS; ++ks) v += qpart[(size_t)(ks*B_+b)*E_ + e];
    qs[e] = v;
  }
  __syncthreads();
  const int wv = tid >> 6, ln = tid & 63;
  for(int l=wv; l<=i; l+=4){
    const float* hl = hist + (size_t)(l*B_+b)*E_;
    float s = 0.f;
    for(int e=ln; e<E_; e+=64) s += qs[e]*hl[e];
    #pragma unroll
    for(int off=32; off; off>>=1) s += __shfl_down(s, off);
    if(ln==0) sc[l] = s;
  }
  __syncthreads();
  if(tid < 64){
    float v  = (tid<=i) ? sc[tid] : -INFINITY;
    float mx = v;
    #pragma unroll
    for(int off=32; off; off>>=1) mx = fmaxf(mx, __shfl_xor(mx, off));
    float ex = (tid<=i) ? expf(v-mx) : 0.f;
    float sm = ex;
    #pragma unroll
    for(int off=32; off; off>>=1) sm += __shfl_xor(sm, off);
    sc[tid] = ex/sm;
  }
  __syncthreads();
  const float* xi = feats + ((size_t)b*T_ + i)*E_;
  for(int e=tid; e<E_; e+=256){
    float ctx = 0.f;
    for(int l=0; l<=i; ++l) ctx += sc[l]*hist[(size_t)(l*B_+b)*E_ + e];
    xc[(size_t)b*E_ + e] = xi[e] + ctx;
  }
}

// ---------------------------------------------------------------------------
// Final classifier: out[b][t][c] = emo_seq[t][b] . cls_W[c] + cls_b[c]
// ---------------------------------------------------------------------------
__global__ void classify(const float* __restrict__ emo_seq, const float* __restrict__ clsW,
                         const float* __restrict__ clsb, float* __restrict__ out)
{
  const int idx = blockIdx.x*256 + threadIdx.x;
  if(idx >= B_*T_*C_) return;
  const int c = idx % C_;
  const int bt = idx / C_;
  const int t = bt % T_, b = bt / T_;
  const float* e = emo_seq + (size_t)(t*B_ + b)*HH_;
  const float* w = clsW + (size_t)c*HH_;
  float s = clsb[c];
  for(int h=0; h<HH_; ++h) s += e[h]*w[h];
  out[idx] = s;
}

// ---------------------------------------------------------------------------
extern "C" void kernel_launch(void* const* d_in, const int* in_sizes, int n_in,
                              void* d_out, int out_size, void* d_ws, size_t ws_size,
                              hipStream_t stream)
{
  const float* input  = (const float*)d_in[0];
  const float* Wih_f  = (const float*)d_in[1];
  const float* Whh_f  = (const float*)d_in[2];
  const float* b_f    = (const float*)d_in[3];
  const float* Wih_b  = (const float*)d_in[4];
  const float* Whh_b  = (const float*)d_in[5];
  const float* b_b    = (const float*)d_in[6];
  const float* W_att  = (const float*)d_in[7];
  const float* g_Wih  = (const float*)d_in[8];
  const float* g_Whh  = (const float*)d_in[9];
  const float* g_bih  = (const float*)d_in[10];
  const float* g_bhh  = (const float*)d_in[11];
  const float* p_Wih  = (const float*)d_in[12];
  const float* p_Whh  = (const float*)d_in[13];
  const float* p_bih  = (const float*)d_in[14];
  const float* p_bhh  = (const float*)d_in[15];
  const float* e_Wih  = (const float*)d_in[16];
  const float* e_Whh  = (const float*)d_in[17];
  const float* e_bih  = (const float*)d_in[18];
  const float* e_bhh  = (const float*)d_in[19];
  const float* cls_W  = (const float*)d_in[20];
  const float* cls_b  = (const float*)d_in[21];

  // Workspace layout (floats). Zero region first (~25.6 MB), total ~50.4 MB.
  float* ws = (float*)d_ws;
  float* hb0     = ws;                                   // [2][2048][512]
  float* cbuf    = hb0    + (size_t)2*N_*H_;             // [2][2048][512]
  float* hist    = cbuf   + (size_t)2*N_*H_;             // [65][32][1024]
  float* party   = hist   + (size_t)(T_+1)*B_*E_;        // [2][32][1024]
  float* emo     = party  + (size_t)2*B_*E_;             // [32][512]
  float* zend    = emo    + (size_t)B_*HH_;
  float* hb1     = zend;                                 // [2][2048][512]
  float* feats   = hb1    + (size_t)2*N_*H_;             // [2048][1024]
  float* emo_seq = feats  + (size_t)N_*E_;               // [64][32][512]
  float* part    = emo_seq+ (size_t)T_*B_*HH_;           // [2][4][32][3072]
  float* qpart   = part   + (size_t)2*4*B_*(3*E_);       // [4][32][1024]
  float* xcbuf   = qpart  + (size_t)4*B_*E_;             // [32][1024]

  hipMemsetAsync(d_ws, 0, (size_t)(zend - ws)*sizeof(float), stream);

  // ---- Phase 1: BiLSTM over words ----
  for(int t=0; t<TW_; ++t){
    float* hin  = (t & 1) ? hb1 : hb0;
    float* hout = (t & 1) ? hb0 : hb1;
    lstm_step<<<dim3(16,64,2), 256, 0, stream>>>(input, Wih_f,Whh_f,b_f, Wih_b,Whh_b,b_b,
                                                 hin, hout, cbuf, feats, t);
  }

  // ---- Phase 2: sequential recurrence over utterances ----
  for(int i=0; i<T_; ++i){
    const int p = i & 1;
    float* party_p = party + (size_t)p*B_*E_;
    float* hist_i  = hist  + (size_t)i*B_*E_;

    // global-state GRU
    GArg ga0{ feats + (size_t)i*E_, party_p, (long)T_*E_, (long)E_, g_Wih, E_, 0 };
    GArg ga1{ hist_i, nullptr, (long)E_, 0, g_Whh, E_, 0 };
    gemm_part<<<dim3(24,4,2), 256, 0, stream>>>(ga0, ga1, 3*E_, 4, part);
    gru_combine<<<dim3(128), 256, 0, stream>>>(part, 3*E_, 4, g_bih, g_bhh,
                                               hist_i, (long)E_,
                                               hist + (size_t)(i+1)*B_*E_, (long)E_,
                                               nullptr, E_);
    // q = x_i @ W_att
    GArg qa{ feats + (size_t)i*E_, nullptr, (long)T_*E_, 0, W_att, E_, 1 };
    gemm_part<<<dim3(8,4,1), 256, 0, stream>>>(qa, qa, E_, 4, qpart);
    // attention -> xc = x_i + context
    att_step<<<dim3(32), 256, 0, stream>>>(qpart, 4, hist, feats, xcbuf, i);

    // party-state GRU (in-place on party[p])
    GArg pa0{ xcbuf, nullptr, (long)E_, 0, p_Wih, E_, 0 };
    GArg pa1{ party_p, nullptr, (long)E_, 0, p_Whh, E_, 0 };
    gemm_part<<<dim3(24,4,2), 256, 0, stream>>>(pa0, pa1, 3*E_, 4, part);
    gru_combine<<<dim3(128), 256, 0, stream>>>(part, 3*E_, 4, p_bih, p_bhh,
                                               party_p, (long)E_, party_p, (long)E_,
                                               nullptr, E_);
    // emotion GRU (in-place on emo, also writes emo_seq[i])
    GArg ea0{ party_p, nullptr, (long)E_, 0, e_Wih, E_, 0 };
    GArg ea1{ emo, nullptr, (long)HH_, 0, e_Whh, HH_, 0 };
    gemm_part<<<dim3(12,4,2), 256, 0, stream>>>(ea0, ea1, 3*HH_, 4, part);
    gru_combine<<<dim3(64), 256, 0, stream>>>(part, 3*HH_, 4, e_bih, e_bhh,
                                              emo, (long)HH_, emo, (long)HH_,
                                              emo_seq + (size_t)i*B_*HH_, HH_);
  }

  // ---- classifier ----
  classify<<<dim3((B_*T_*C_+255)/256), 256, 0, stream>>>(emo_seq, cls_W, cls_b, (float*)d_out);
}

// Round 3
// 3502.350 us; speedup vs baseline: 4.7687x; 4.7687x over previous
//
#include <hip/hip_runtime.h>
#include <math.h>

#define B_  32
#define T_  64
#define TW_ 32
#define EW_ 300
#define H_  512
#define E_  1024
#define HH_ 512
#define C_  7
#define N_  2048   // B*T

typedef float f32x4 __attribute__((ext_vector_type(4)));
typedef short s16x8 __attribute__((ext_vector_type(8)));

__device__ __forceinline__ float sigm(float x){ return 1.f/(1.f+expf(-x)); }
__device__ __forceinline__ float bf2f(unsigned short u){
  union{float f; unsigned v;} x; x.v = ((unsigned)u)<<16; return x.f;
}
__device__ __forceinline__ unsigned short f2bf(float f){
  union{float f; unsigned v;} x; x.f = f;
  unsigned r = x.v + 0x7FFF + ((x.v>>16)&1);
  return (unsigned short)(r>>16);
}

// ===========================================================================
// Pre-pass conversion kernels
// ===========================================================================
__global__ __launch_bounds__(256) void k_pack_lstm(
    const float* __restrict__ Wih_f, const float* __restrict__ Whh_f,
    const float* __restrict__ Wih_b, const float* __restrict__ Whh_b,
    unsigned short* __restrict__ Wpack)
{
  size_t idx = (size_t)blockIdx.x*256 + threadIdx.x;
  if(idx >= (size_t)2*2048*832) return;
  int dir = (int)(idx / (2048*832));
  int rem = (int)(idx % (2048*832));
  int r = rem / 832, c = rem % 832;
  const float* Wih = dir ? Wih_b : Wih_f;
  const float* Whh = dir ? Whh_b : Whh_f;
  float v = (c < 320) ? ((c < EW_) ? Wih[(size_t)r*EW_ + c] : 0.f)
                      : Whh[(size_t)r*H_ + (c-320)];
  Wpack[idx] = f2bf(v);
}

__global__ __launch_bounds__(256) void k_f2bf(const float* __restrict__ src,
                                              unsigned short* __restrict__ dst, int n)
{
  int idx = blockIdx.x*256 + threadIdx.x;
  if(idx < n) dst[idx] = f2bf(src[idx]);
}

__global__ __launch_bounds__(256) void k_wattT(const float* __restrict__ W,
                                               unsigned short* __restrict__ dst)
{
  int idx = blockIdx.x*256 + threadIdx.x;
  if(idx >= E_*E_) return;
  int j = idx >> 10, k = idx & 1023;
  dst[idx] = f2bf(W[(size_t)k*E_ + j]);   // dst[j][k] = W[k][j]
}

// ===========================================================================
// Phase 1: BiLSTM step with bf16 MFMA.
// grid (16 panels = m-tile*2+dir, 32 n-tiles), 256 thr (4 waves).
// Block tile: 64n x (64m x 4 gates). Wave w: m-sub [16w,16w+16) of ALL gates
// -> each lane holds i,f,g,o for its (n,m) -> exchange-free cell update.
// ===========================================================================
__global__ __launch_bounds__(256) void lstm_mfma(
    const float* __restrict__ xin, const unsigned short* __restrict__ Wpack,
    const float* __restrict__ b_f, const float* __restrict__ b_b,
    const unsigned short* __restrict__ hbf_in, unsigned short* __restrict__ hbf_out,
    float* __restrict__ cb, unsigned short* __restrict__ featsbf, int t)
{
  const int panel = blockIdx.x;
  const int dir = panel & 1, mt = panel >> 1;
  const int n0 = blockIdx.y * 64;
  const int M0 = mt * 64;
  const int wt = dir ? (TW_-1-t) : t;
  const unsigned short* Wp = Wpack + (size_t)dir*2048*832;

  __shared__ __align__(16) unsigned short As[64*40];
  __shared__ __align__(16) unsigned short Ws[256*40];

  const int tid = threadIdx.x;
  const int w = tid >> 6, l = tid & 63;
  const int lr = l & 15, lk = (l >> 4) * 8;

  f32x4 acc[4][4];
  #pragma unroll
  for(int a=0;a<4;a++)
    #pragma unroll
    for(int g=0;g<4;g++) acc[a][g] = (f32x4){0.f,0.f,0.f,0.f};

  const int arow = tid >> 2, ak8 = (tid & 3) * 8;
  const int wg = tid >> 6, wml = tid & 63;
  const unsigned short* wsrc = Wp + (size_t)(wg*H_ + M0 + wml)*832;

  for(int kc=0; kc<26; ++kc){
    // ---- stage A (64n x 32k) ----
    s16x8 av;
    if(kc < 10){
      const float* xs = xin + ((size_t)(n0+arow)*TW_ + wt)*EW_;
      const int kb = kc*32 + ak8;
      #pragma unroll
      for(int j=0;j<8;j++){
        int k = kb + j;
        float v = (k < EW_) ? xs[k] : 0.f;
        av[j] = (short)f2bf(v);
      }
    } else {
      av = *(const s16x8*)&hbf_in[(size_t)dir*N_*H_ + (size_t)(n0+arow)*H_ + (kc-10)*32 + ak8];
    }
    *(s16x8*)&As[arow*40 + ak8] = av;
    // ---- stage W (256 gate-rows x 32k) ----
    {
      const unsigned short* wr = wsrc + kc*32;
      #pragma unroll
      for(int h=0; h<4; ++h)
        *(s16x8*)&Ws[tid*40 + h*8] = *(const s16x8*)&wr[h*8];
    }
    __syncthreads();
    s16x8 a[4];
    #pragma unroll
    for(int nf=0; nf<4; ++nf) a[nf] = *(const s16x8*)&As[(nf*16 + lr)*40 + lk];
    #pragma unroll
    for(int g=0; g<4; ++g){
      s16x8 bv = *(const s16x8*)&Ws[(g*64 + w*16 + lr)*40 + lk];
      #pragma unroll
      for(int nf=0; nf<4; ++nf)
        acc[nf][g] = __builtin_amdgcn_mfma_f32_16x16x32_bf16(a[nf], bv, acc[nf][g], 0,0,0);
    }
    __syncthreads();
  }

  // ---- cell update epilogue ----
  const float* bias = dir ? b_b : b_f;
  const int m = M0 + w*16 + lr;
  const float bi = bias[m], bfv = bias[H_+m], bg = bias[2*H_+m], bo = bias[3*H_+m];
  float* cbp = cb + (size_t)dir*N_*H_;
  unsigned short* ho = hbf_out + (size_t)dir*N_*H_;
  #pragma unroll
  for(int nf=0; nf<4; ++nf){
    #pragma unroll
    for(int r=0; r<4; ++r){
      const int n = n0 + nf*16 + (l>>4)*4 + r;
      float gi = acc[nf][0][r] + bi;
      float gf = acc[nf][1][r] + bfv;
      float gc = acc[nf][2][r] + bg;
      float go = acc[nf][3][r] + bo;
      float c_old = cbp[(size_t)n*H_ + m];
      float c2 = sigm(gf)*c_old + sigm(gi)*tanhf(gc);
      float h2 = sigm(go)*tanhf(c2);
      cbp[(size_t)n*H_ + m] = c2;
      if(t == TW_-1) featsbf[(size_t)n*E_ + dir*H_ + m] = f2bf(h2);
      else           ho[(size_t)n*H_ + m] = f2bf(h2);
    }
  }
}

// ===========================================================================
// q = feats @ W_att  (one-time, bf16 MFMA, fp32 out)
// ===========================================================================
__global__ __launch_bounds__(256) void k_qgemm(const unsigned short* __restrict__ featsbf,
                                               const unsigned short* __restrict__ WattT,
                                               float* __restrict__ q)
{
  const int n0 = blockIdx.x*64, j0 = blockIdx.y*64;
  __shared__ __align__(16) unsigned short As[64*40];
  __shared__ __align__(16) unsigned short Bs[64*40];
  const int tid = threadIdx.x;
  const int w = tid>>6, l = tid&63, lr = l&15, lk = (l>>4)*8;
  const int arow = tid>>2, ak8 = (tid&3)*8;

  f32x4 acc[4];
  #pragma unroll
  for(int i=0;i<4;i++) acc[i] = (f32x4){0.f,0.f,0.f,0.f};

  for(int kc=0; kc<32; ++kc){
    *(s16x8*)&As[arow*40 + ak8] = *(const s16x8*)&featsbf[(size_t)(n0+arow)*E_ + kc*32 + ak8];
    *(s16x8*)&Bs[arow*40 + ak8] = *(const s16x8*)&WattT[(size_t)(j0+arow)*E_ + kc*32 + ak8];
    __syncthreads();
    s16x8 av = *(const s16x8*)&As[(w*16 + lr)*40 + lk];
    #pragma unroll
    for(int mf=0; mf<4; ++mf){
      s16x8 bv = *(const s16x8*)&Bs[(mf*16 + lr)*40 + lk];
      acc[mf] = __builtin_amdgcn_mfma_f32_16x16x32_bf16(av, bv, acc[mf], 0,0,0);
    }
    __syncthreads();
  }
  #pragma unroll
  for(int mf=0; mf<4; ++mf)
    #pragma unroll
    for(int r=0; r<4; ++r){
      int n = n0 + w*16 + (l>>4)*4 + r;
      q[(size_t)n*E_ + j0 + mf*16 + lr] = acc[mf][r];
    }
}

// ===========================================================================
// Phase 2 building blocks
// ===========================================================================
struct GArg2 {
  const unsigned short* xA; const unsigned short* xB;
  long ldA; long ldB;
  const unsigned short* W; int K;
};

// M=32 split-K partial GEMM, bf16 MFMA. Block: 32n x 128gc, 4 waves.
__device__ __forceinline__ void gemm32_body(const GArg2 a, int R, int xt, int ks,
                                            int KS, int z, float* __restrict__ part,
                                            char* smem)
{
  unsigned short* Xs = (unsigned short*)smem;          // [32][40]
  unsigned short* Ws = (unsigned short*)smem + 32*40;  // [128][40]
  const int Kc = a.K / KS;
  const int nchunk = Kc >> 5;
  const int kb0 = ks * Kc;
  const int tid = threadIdx.x;
  const int w = tid>>6, l = tid&63, lr = l&15, lk = (l>>4)*8;

  f32x4 acc[2][2];
  acc[0][0]=(f32x4){0,0,0,0}; acc[0][1]=(f32x4){0,0,0,0};
  acc[1][0]=(f32x4){0,0,0,0}; acc[1][1]=(f32x4){0,0,0,0};

  for(int kc=0; kc<nchunk; ++kc){
    const int kb = kb0 + kc*32;
    if(tid < 128){
      const int row = tid>>2, k8 = (tid&3)*8;
      s16x8 xv = *(const s16x8*)&a.xA[(size_t)row*a.ldA + kb + k8];
      if(a.xB){
        s16x8 yv = *(const s16x8*)&a.xB[(size_t)row*a.ldB + kb + k8];
        #pragma unroll
        for(int j=0;j<8;j++)
          xv[j] = (short)f2bf(bf2f((unsigned short)xv[j]) + bf2f((unsigned short)yv[j]));
      }
      *(s16x8*)&Xs[row*40 + k8] = xv;
    }
    {
      const int row = tid>>1, h = (tid&1)*16;
      const unsigned short* wr = a.W + (size_t)(xt*128 + row)*a.K + kb + h;
      *(s16x8*)&Ws[row*40 + h]     = *(const s16x8*)&wr[0];
      *(s16x8*)&Ws[row*40 + h + 8] = *(const s16x8*)&wr[8];
    }
    __syncthreads();
    s16x8 av0 = *(const s16x8*)&Xs[lr*40 + lk];
    s16x8 av1 = *(const s16x8*)&Xs[(16+lr)*40 + lk];
    s16x8 bv0 = *(const s16x8*)&Ws[(w*32 + lr)*40 + lk];
    s16x8 bv1 = *(const s16x8*)&Ws[(w*32 + 16 + lr)*40 + lk];
    acc[0][0] = __builtin_amdgcn_mfma_f32_16x16x32_bf16(av0, bv0, acc[0][0], 0,0,0);
    acc[0][1] = __builtin_amdgcn_mfma_f32_16x16x32_bf16(av0, bv1, acc[0][1], 0,0,0);
    acc[1][0] = __builtin_amdgcn_mfma_f32_16x16x32_bf16(av1, bv0, acc[1][0], 0,0,0);
    acc[1][1] = __builtin_amdgcn_mfma_f32_16x16x32_bf16(av1, bv1, acc[1][1], 0,0,0);
    __syncthreads();
  }
  float* dst = part + (size_t)((z*KS + ks)*B_)*R + xt*128 + w*32;
  #pragma unroll
  for(int nf=0; nf<2; ++nf)
    #pragma unroll
    for(int mf=0; mf<2; ++mf)
      #pragma unroll
      for(int r=0; r<4; ++r){
        int n = nf*16 + (l>>4)*4 + r;
        dst[(size_t)n*R + mf*16 + lr] = acc[nf][mf][r];
      }
}

// attention body: one block per b (256 thr). q row is n = b*T_ + i  (BUGFIX)
__device__ __forceinline__ void att_body(const float* __restrict__ q,
                                         const unsigned short* __restrict__ histbf,
                                         const unsigned short* __restrict__ featsbf,
                                         unsigned short* __restrict__ xcbf,
                                         int i, int b, char* smem)
{
  float* qs = (float*)smem;      // 1024
  float* sc = qs + E_;           // 64
  const int tid = threadIdx.x;
  *(float4*)&qs[tid*4] = *(const float4*)&q[((size_t)b*T_ + i)*E_ + tid*4];
  __syncthreads();
  const int wv = tid>>6, ln = tid&63;
  for(int L = wv; L <= i; L += 4){
    const unsigned short* hl = histbf + ((size_t)L*B_ + b)*E_;
    float s = 0.f;
    s16x8 h0 = *(const s16x8*)&hl[ln*16];
    s16x8 h1 = *(const s16x8*)&hl[ln*16 + 8];
    #pragma unroll
    for(int j=0;j<8;j++){
      s += qs[ln*16 + j]     * bf2f((unsigned short)h0[j]);
      s += qs[ln*16 + 8 + j] * bf2f((unsigned short)h1[j]);
    }
    #pragma unroll
    for(int off=32; off; off>>=1) s += __shfl_down(s, off);
    if(ln == 0) sc[L] = s;
  }
  __syncthreads();
  if(tid < 64){
    float v  = (tid <= i) ? sc[tid] : -INFINITY;
    float mx = v;
    #pragma unroll
    for(int off=32; off; off>>=1) mx = fmaxf(mx, __shfl_xor(mx, off));
    float ex = (tid <= i) ? expf(v - mx) : 0.f;
    float sm = ex;
    #pragma unroll
    for(int off=32; off; off>>=1) sm += __shfl_xor(sm, off);
    sc[tid] = ex / sm;
  }
  __syncthreads();
  const int e4 = tid*4;
  float c0=0.f, c1=0.f, c2=0.f, c3=0.f;
  for(int L=0; L<=i; ++L){
    float wl = sc[L];
    short4 hv = *(const short4*)&histbf[((size_t)L*B_ + b)*E_ + e4];
    c0 += wl*bf2f((unsigned short)hv.x);
    c1 += wl*bf2f((unsigned short)hv.y);
    c2 += wl*bf2f((unsigned short)hv.z);
    c3 += wl*bf2f((unsigned short)hv.w);
  }
  const unsigned short* xi = featsbf + ((size_t)b*T_ + i)*E_ + e4;
  xcbf[(size_t)b*E_ + e4 + 0] = f2bf(bf2f(xi[0]) + c0);
  xcbf[(size_t)b*E_ + e4 + 1] = f2bf(bf2f(xi[1]) + c1);
  xcbf[(size_t)b*E_ + e4 + 2] = f2bf(bf2f(xi[2]) + c2);
  xcbf[(size_t)b*E_ + e4 + 3] = f2bf(bf2f(xi[3]) + c3);
}

// GRU combine: reduce split-K partials + nonlinearity. fp32 master state in/out,
// bf16 mirror out (feeds next GEMMs).
__device__ __forceinline__ void gru_comb(const float* __restrict__ part, int R, int J, int KS,
                                         const float* __restrict__ bih, const float* __restrict__ bhh,
                                         const float* __restrict__ hprev_f,
                                         float* __restrict__ dst_f,
                                         unsigned short* __restrict__ dstbf,
                                         float* __restrict__ dst_seq, int idx)
{
  const int b = idx / J, e = idx - b*J;
  float ir=0.f, iz=0.f, in_=0.f, hr=0.f, hz=0.f, hn=0.f;
  for(int ks=0; ks<KS; ++ks){
    const float* p0 = part + (size_t)(ks*B_ + b)*R;
    const float* p1 = part + (size_t)((KS+ks)*B_ + b)*R;
    ir += p0[e]; iz += p0[J+e]; in_ += p0[2*J+e];
    hr += p1[e]; hz += p1[J+e]; hn  += p1[2*J+e];
  }
  ir += bih[e]; iz += bih[J+e]; in_ += bih[2*J+e];
  hr += bhh[e]; hz += bhh[J+e]; hn  += bhh[2*J+e];
  const float r = sigm(ir + hr);
  const float z = sigm(iz + hz);
  const float n = tanhf(in_ + r*hn);
  const float hp = hprev_f[(size_t)b*J + e];
  const float h2 = (1.f - z)*n + z*hp;
  dst_f[(size_t)b*J + e] = h2;
  dstbf[(size_t)b*J + e] = f2bf(h2);
  if(dst_seq) dst_seq[(size_t)b*J + e] = h2;
}

// S1: [g-gemm(i) | e-gemm(i-1) | att(i)]   grid (38, 8, 2)
__global__ __launch_bounds__(256) void k_s1(GArg2 g0, GArg2 g1, GArg2 e0, GArg2 e1,
    float* __restrict__ part_gp, float* __restrict__ part_e,
    const float* __restrict__ q, const unsigned short* __restrict__ histbf,
    const unsigned short* __restrict__ featsbf, unsigned short* __restrict__ xcbf, int i)
{
  __shared__ __align__(16) char smem[12800];
  const int x = blockIdx.x, ks = blockIdx.y, z = blockIdx.z;
  if(x < 24){
    if(i >= T_) return;
    gemm32_body(z ? g1 : g0, 3*E_, x, ks, 8, z, part_gp, smem);
  } else if(x < 36){
    if(i < 1) return;
    gemm32_body(z ? e1 : e0, 3*HH_, x-24, ks, 8, z, part_e, smem);
  } else {
    if(i >= T_) return;
    const int b = (x-36)*16 + ks*2 + z;
    att_body(q, histbf, featsbf, xcbf, i, b, smem);
  }
}

// S2: [g-combine(i) | e-combine(i-1)]   grid (192)
__global__ __launch_bounds__(256) void k_s2(const float* __restrict__ part_gp,
    const float* __restrict__ part_e,
    const float* __restrict__ g_bih, const float* __restrict__ g_bhh,
    const float* __restrict__ e_bih, const float* __restrict__ e_bhh,
    const float* __restrict__ gf_prev, float* __restrict__ gf_next,
    unsigned short* __restrict__ histbf,
    float* __restrict__ emof, unsigned short* __restrict__ emobf,
    float* __restrict__ emo_seq, int i)
{
  const int x = blockIdx.x;
  if(x < 128){
    if(i >= T_) return;
    const int idx = x*256 + threadIdx.x;          // < 32768
    gru_comb(part_gp, 3*E_, E_, 8, g_bih, g_bhh,
             gf_prev, gf_next, histbf + (size_t)(i+1)*B_*E_, nullptr, idx);
  } else {
    const int ie = i - 1;
    if(ie < 0) return;
    const int idx = (x-128)*256 + threadIdx.x;    // < 16384
    gru_comb(part_e, 3*HH_, HH_, 8, e_bih, e_bhh,
             emof, emof, emobf, emo_seq + (size_t)ie*B_*HH_, idx);
  }
}

// S3: p-gemm   grid (24, 8, 2)
__global__ __launch_bounds__(256) void k_s3(GArg2 p0, GArg2 p1, float* __restrict__ part_gp)
{
  __shared__ __align__(16) char smem[12800];
  gemm32_body(blockIdx.z ? p1 : p0, 3*E_, blockIdx.x, blockIdx.y, 8, blockIdx.z, part_gp, smem);
}

// S4: p-combine   grid (128)
__global__ __launch_bounds__(256) void k_s4(const float* __restrict__ part_gp,
    const float* __restrict__ p_bih, const float* __restrict__ p_bhh,
    float* __restrict__ partyf_p, unsigned short* __restrict__ partybf_p)
{
  const int idx = blockIdx.x*256 + threadIdx.x;
  gru_comb(part_gp, 3*E_, E_, 8, p_bih, p_bhh, partyf_p, partyf_p, partybf_p, nullptr, idx);
}

// classifier
__global__ __launch_bounds__(256) void classify(const float* __restrict__ emo_seq,
    const float* __restrict__ clsW, const float* __restrict__ clsb, float* __restrict__ out)
{
  const int idx = blockIdx.x*256 + threadIdx.x;
  if(idx >= B_*T_*C_) return;
  const int c = idx % C_;
  const int bt = idx / C_;
  const int t = bt % T_, b = bt / T_;
  const float* e = emo_seq + (size_t)(t*B_ + b)*HH_;
  const float* w = clsW + (size_t)c*HH_;
  float s = clsb[c];
  for(int h=0; h<HH_; ++h) s += e[h]*w[h];
  out[idx] = s;
}

// ===========================================================================
extern "C" void kernel_launch(void* const* d_in, const int* in_sizes, int n_in,
                              void* d_out, int out_size, void* d_ws, size_t ws_size,
                              hipStream_t stream)
{
  const float* input  = (const float*)d_in[0];
  const float* Wih_f  = (const float*)d_in[1];
  const float* Whh_f  = (const float*)d_in[2];
  const float* b_f    = (const float*)d_in[3];
  const float* Wih_b  = (const float*)d_in[4];
  const float* Whh_b  = (const float*)d_in[5];
  const float* b_b    = (const float*)d_in[6];
  const float* W_att  = (const float*)d_in[7];
  const float* g_Wih  = (const float*)d_in[8];
  const float* g_Whh  = (const float*)d_in[9];
  const float* g_bih  = (const float*)d_in[10];
  const float* g_bhh  = (const float*)d_in[11];
  const float* p_Wih  = (const float*)d_in[12];
  const float* p_Whh  = (const float*)d_in[13];
  const float* p_bih  = (const float*)d_in[14];
  const float* p_bhh  = (const float*)d_in[15];
  const float* e_Wih  = (const float*)d_in[16];
  const float* e_Whh  = (const float*)d_in[17];
  const float* e_bih  = (const float*)d_in[18];
  const float* e_bhh  = (const float*)d_in[19];
  const float* cls_W  = (const float*)d_in[20];
  const float* cls_b  = (const float*)d_in[21];

  // ---- workspace layout (bytes) ----
  char* base = (char*)d_ws;
  size_t off = 0;
  auto alloc = [&](size_t bytes)->char*{
    char* p = base + off; off += (bytes + 255) & ~(size_t)255; return p;
  };
  unsigned short* Wpack   = (unsigned short*)alloc((size_t)2*2048*832*2);
  unsigned short* hbfA    = (unsigned short*)alloc((size_t)2*N_*H_*2);
  unsigned short* hbfB    = (unsigned short*)alloc((size_t)2*N_*H_*2);
  float*          cb      = (float*)alloc((size_t)2*N_*H_*4);
  unsigned short* featsbf = (unsigned short*)alloc((size_t)N_*E_*2);
  float*          q       = (float*)alloc((size_t)N_*E_*4);
  unsigned short* WattT   = (unsigned short*)alloc((size_t)E_*E_*2);
  unsigned short* gWih    = (unsigned short*)alloc((size_t)3*E_*E_*2);
  unsigned short* gWhh    = (unsigned short*)alloc((size_t)3*E_*E_*2);
  unsigned short* pWih    = (unsigned short*)alloc((size_t)3*E_*E_*2);
  unsigned short* pWhh    = (unsigned short*)alloc((size_t)3*E_*E_*2);
  unsigned short* eWih    = (unsigned short*)alloc((size_t)3*HH_*E_*2);
  unsigned short* eWhh    = (unsigned short*)alloc((size_t)3*HH_*HH_*2);
  unsigned short* histbf  = (unsigned short*)alloc((size_t)(T_+1)*B_*E_*2);
  float*          gfbuf   = (float*)alloc((size_t)2*B_*E_*4);     // fp32 g-state ping-pong
  float*          partyf  = (float*)alloc((size_t)2*B_*E_*4);     // fp32 party master
  unsigned short* partybf = (unsigned short*)alloc((size_t)2*B_*E_*2);
  float*          emof    = (float*)alloc((size_t)B_*HH_*4);      // fp32 emo master
  unsigned short* emobf   = (unsigned short*)alloc((size_t)B_*HH_*2);
  float*          emo_seq = (float*)alloc((size_t)T_*B_*HH_*4);
  unsigned short* xcbf    = (unsigned short*)alloc((size_t)B_*E_*2);
  float*          part_gp = (float*)alloc((size_t)16*B_*3*E_*4);
  float*          part_e  = (float*)alloc((size_t)16*B_*3*HH_*4);

  // ---- zero-init recurrent state ----
  hipMemsetAsync(hbfA,    0, (size_t)2*N_*H_*2, stream);
  hipMemsetAsync(cb,      0, (size_t)2*N_*H_*4, stream);
  hipMemsetAsync(histbf,  0, (size_t)B_*E_*2, stream);        // slice 0 only
  hipMemsetAsync(gfbuf,   0, (size_t)B_*E_*4, stream);        // slice 0 only
  hipMemsetAsync(partyf,  0, (size_t)2*B_*E_*4, stream);
  hipMemsetAsync(partybf, 0, (size_t)2*B_*E_*2, stream);
  hipMemsetAsync(emof,    0, (size_t)B_*HH_*4, stream);
  hipMemsetAsync(emobf,   0, (size_t)B_*HH_*2, stream);

  // ---- pre-pass conversions ----
  k_pack_lstm<<<dim3((2*2048*832+255)/256), 256, 0, stream>>>(Wih_f, Whh_f, Wih_b, Whh_b, Wpack);
  k_f2bf<<<dim3((3*E_*E_+255)/256), 256, 0, stream>>>(g_Wih, gWih, 3*E_*E_);
  k_f2bf<<<dim3((3*E_*E_+255)/256), 256, 0, stream>>>(g_Whh, gWhh, 3*E_*E_);
  k_f2bf<<<dim3((3*E_*E_+255)/256), 256, 0, stream>>>(p_Wih, pWih, 3*E_*E_);
  k_f2bf<<<dim3((3*E_*E_+255)/256), 256, 0, stream>>>(p_Whh, pWhh, 3*E_*E_);
  k_f2bf<<<dim3((3*HH_*E_+255)/256), 256, 0, stream>>>(e_Wih, eWih, 3*HH_*E_);
  k_f2bf<<<dim3((3*HH_*HH_+255)/256), 256, 0, stream>>>(e_Whh, eWhh, 3*HH_*HH_);
  k_wattT<<<dim3((E_*E_+255)/256), 256, 0, stream>>>(W_att, WattT);

  // ---- Phase 1: BiLSTM ----
  for(int t=0; t<TW_; ++t){
    unsigned short* hin  = (t & 1) ? hbfB : hbfA;
    unsigned short* hout = (t & 1) ? hbfA : hbfB;
    lstm_mfma<<<dim3(16, 32), 256, 0, stream>>>(input, Wpack, b_f, b_b,
                                                hin, hout, cb, featsbf, t);
  }

  // ---- q = feats @ W_att (all steps at once) ----
  k_qgemm<<<dim3(32, 16), 256, 0, stream>>>(featsbf, WattT, q);

  // ---- Phase 2: pipelined recurrence, 4 launches/step ----
  for(int i=0; i<=T_; ++i){
    const int p  = i & 1;
    const int pe = (i-1) & 1;
    GArg2 ga0{ featsbf + (size_t)i*E_, partybf + (size_t)p*B_*E_, (long)T_*E_, (long)E_, gWih, E_ };
    GArg2 ga1{ histbf + (size_t)i*B_*E_, nullptr, (long)E_, 0, gWhh, E_ };
    GArg2 ea0{ partybf + (size_t)pe*B_*E_, nullptr, (long)E_, 0, eWih, E_ };
    GArg2 ea1{ emobf, nullptr, (long)HH_, 0, eWhh, HH_ };
    k_s1<<<dim3(38, 8, 2), 256, 0, stream>>>(ga0, ga1, ea0, ea1, part_gp, part_e,
                                             q, histbf, featsbf, xcbf, i);
    k_s2<<<dim3(192), 256, 0, stream>>>(part_gp, part_e, g_bih, g_bhh, e_bih, e_bhh,
                                        gfbuf + (size_t)(i&1)*B_*E_,
                                        gfbuf + (size_t)((i+1)&1)*B_*E_,
                                        histbf, emof, emobf, emo_seq, i);
    if(i < T_){
      GArg2 pa0{ xcbf, nullptr, (long)E_, 0, pWih, E_ };
      GArg2 pa1{ partybf + (size_t)p*B_*E_, nullptr, (long)E_, 0, pWhh, E_ };
      k_s3<<<dim3(24, 8, 2), 256, 0, stream>>>(pa0, pa1, part_gp);
      k_s4<<<dim3(128), 256, 0, stream>>>(part_gp, p_bih, p_bhh,
                                          partyf + (size_t)p*B_*E_,
                                          partybf + (size_t)p*B_*E_);
    }
  }

  // ---- classifier ----
  classify<<<dim3((B_*T_*C_+255)/256), 256, 0, stream>>>(emo_seq, cls_W, cls_b, (float*)d_out);
}

// Round 4
// 2919.716 us; speedup vs baseline: 5.7203x; 1.1996x over previous
//
#include <hip/hip_runtime.h>
#include <math.h>

#define B_  32
#define T_  64
#define TW_ 32
#define EW_ 300
#define H_  512
#define E_  1024
#define HH_ 512
#define C_  7
#define N_  2048   // B*T

typedef float f32x4 __attribute__((ext_vector_type(4)));
typedef short s16x8 __attribute__((ext_vector_type(8)));
typedef unsigned short u16;
typedef unsigned int u32;

__device__ __forceinline__ float sigm(float x){ return 1.f/(1.f+expf(-x)); }
__device__ __forceinline__ float bf2f(u16 u){
  union{float f; unsigned v;} x; x.v = ((unsigned)u)<<16; return x.f;
}
__device__ __forceinline__ u16 f2bf(float f){
  union{float f; unsigned v;} x; x.f = f;
  unsigned r = x.v + 0x7FFF + ((x.v>>16)&1);
  return (u16)(r>>16);
}
// async 16B global->LDS (dest: wave-uniform base + lane*16)
__device__ __forceinline__ void g2lds16(const void* g, void* l){
  __builtin_amdgcn_global_load_lds((const __attribute__((address_space(1))) u32*)g,
                                   (__attribute__((address_space(3))) u32*)l, 16, 0, 0);
}

// ===========================================================================
// Pre-pass conversion kernels
// ===========================================================================
// Wpack2[((dir*16+mt)*128 + p)*832 + k], p = g*32 + ml, rows R = g*512+mt*32+ml
__global__ __launch_bounds__(256) void k_pack_lstm(
    const float* __restrict__ Wih_f, const float* __restrict__ Whh_f,
    const float* __restrict__ Wih_b, const float* __restrict__ Whh_b,
    u16* __restrict__ Wpack2)
{
  size_t idx = (size_t)blockIdx.x*256 + threadIdx.x;
  if(idx >= (size_t)4096*832) return;
  int k   = (int)(idx % 832);
  int row = (int)(idx / 832);          // (dir*16+mt)*128 + p
  int p   = row & 127;
  int pan = row >> 7;                  // dir*16+mt
  int dir = pan >> 4, mt = pan & 15;
  int g = p >> 5, ml = p & 31;
  int R = g*512 + mt*32 + ml;
  const float* Wih = dir ? Wih_b : Wih_f;
  const float* Whh = dir ? Whh_b : Whh_f;
  float v = (k < 320) ? ((k < EW_) ? Wih[(size_t)R*EW_ + k] : 0.f)
                      : Whh[(size_t)R*H_ + (k-320)];
  Wpack2[idx] = f2bf(v);
}

__global__ __launch_bounds__(256) void k_f2bf(const float* __restrict__ src,
                                              u16* __restrict__ dst, int n)
{
  int idx = blockIdx.x*256 + threadIdx.x;
  if(idx < n) dst[idx] = f2bf(src[idx]);
}

__global__ __launch_bounds__(256) void k_wattT(const float* __restrict__ W,
                                               u16* __restrict__ dst)
{
  int idx = blockIdx.x*256 + threadIdx.x;
  if(idx >= E_*E_) return;
  int j = idx >> 10, k = idx & 1023;
  dst[idx] = f2bf(W[(size_t)k*E_ + j]);   // dst[j][k] = W[k][j]
}

// ===========================================================================
// Phase 1: BiLSTM step, m97-style: 128n x 128c (32m x 4 gates), BK=32,
// dbuf LDS, 1 barrier/chunk, global_load_lds for W + h, reg-staged x chunks.
// grid (32 panels = dir + 2*?; panel = mt*2+dir? -> panel=blockIdx.x: dir=panel&1,
// mt=panel>>1), 16 n-tiles. 4 waves: wn=w>>1 (64n), wm=w&1 (16m, all 4 gates).
// ===========================================================================
__global__ __launch_bounds__(256) void lstm2(
    const float* __restrict__ xin, const u16* __restrict__ Wpack2,
    const float* __restrict__ b_f, const float* __restrict__ b_b,
    const u16* __restrict__ hbf_in, u16* __restrict__ hbf_out,
    float* __restrict__ cb, u16* __restrict__ featsbf, int t)
{
  const int panel = blockIdx.x;            // 0..31
  const int dir = panel & 1, mt = panel >> 1;
  const int n0 = blockIdx.y * 128;
  const int wt = dir ? (TW_-1-t) : t;
  const u16* Wpan = Wpack2 + (size_t)(dir*16+mt)*128*832;
  const u16* hin_d = hbf_in + (size_t)dir*N_*H_;

  __shared__ __align__(16) u16 As[2][128*32];
  __shared__ __align__(16) u16 Bs[2][128*32];

  const int tid = threadIdx.x;
  const int w = tid >> 6, l = tid & 63;
  const int lr = l & 15, lh = l >> 4;      // lh 0..3
  const int wn = w >> 1, wm = w & 1;
  const int xrow = tid >> 1, khalf = (tid & 1)*16;   // x staging

  f32x4 acc[4][4];
  #pragma unroll
  for(int a=0;a<4;a++)
    #pragma unroll
    for(int g=0;g<4;g++) acc[a][g] = (f32x4){0.f,0.f,0.f,0.f};

  // ---- staging helpers ----
  auto issueW = [&](int kc, int b){
    #pragma unroll
    for(int c=0;c<2;++c){
      const int cc = w*2 + c;              // 0..7, 16 rows each
      const char* g = (const char*)Wpan + (size_t)(cc*16 + (l>>2))*1664 + kc*64 + (l&3)*16;
      g2lds16(g, (char*)&Bs[b][0] + cc*1024);
    }
  };
  auto issueAh = [&](int kc, int b){       // kc in [10,26)
    #pragma unroll
    for(int c=0;c<2;++c){
      const int cc = w*2 + c;
      const char* g = (const char*)hin_d + (size_t)(n0 + cc*16 + (l>>2))*1024 + (kc-10)*64 + (l&3)*16;
      g2lds16(g, (char*)&As[b][0] + cc*1024);
    }
  };
  auto loadXx = [&](int kc, float4* xv4){  // kc in [0,10)
    const float* xs = xin + ((size_t)(n0 + xrow)*TW_ + wt)*EW_;
    const int gk = kc*32 + khalf;
    #pragma unroll
    for(int j=0;j<4;++j){
      const int k = gk + j*4;
      if(k + 3 < EW_) xv4[j] = *(const float4*)&xs[k];
      else {
        float4 tmp = {0.f,0.f,0.f,0.f};
        if(k   < EW_) tmp.x = xs[k];
        if(k+1 < EW_) tmp.y = xs[k+1];
        if(k+2 < EW_) tmp.z = xs[k+2];
        xv4[j] = tmp;
      }
    }
  };
  auto finishXx = [&](const float4* xv4, int b){
    const float* xf = (const float*)xv4;
    s16x8 o0, o1;
    #pragma unroll
    for(int j=0;j<8;++j){ o0[j] = (short)f2bf(xf[j]); o1[j] = (short)f2bf(xf[8+j]); }
    *(s16x8*)&As[b][xrow*32 + khalf]     = o0;
    *(s16x8*)&As[b][xrow*32 + khalf + 8] = o1;
  };

  // ---- prologue: chunk 0 (x) ----
  {
    issueW(0, 0);
    float4 xv4[4];
    loadXx(0, xv4);
    finishXx(xv4, 0);
  }
  __syncthreads();

  // ---- main loop: 26 chunks, 1 barrier each ----
  for(int kc=0; kc<26; ++kc){
    const int cur = kc & 1, nxt = cur ^ 1;
    const int kn = kc + 1;
    float4 xv4[4];
    const bool prex = (kn < 10);
    if(kn < 26){
      issueW(kn, nxt);
      if(prex) loadXx(kn, xv4);
      else     issueAh(kn, nxt);
    }
    s16x8 av[4], bv[4];
    #pragma unroll
    for(int nf=0; nf<4; ++nf)
      av[nf] = *(const s16x8*)&As[cur][(wn*64 + nf*16 + lr)*32 + lh*8];
    #pragma unroll
    for(int g=0; g<4; ++g)
      bv[g] = *(const s16x8*)&Bs[cur][(g*32 + wm*16 + lr)*32 + lh*8];
    #pragma unroll
    for(int g=0; g<4; ++g)
      #pragma unroll
      for(int nf=0; nf<4; ++nf)
        acc[nf][g] = __builtin_amdgcn_mfma_f32_16x16x32_bf16(av[nf], bv[g], acc[nf][g], 0,0,0);
    if(prex) finishXx(xv4, nxt);
    __syncthreads();
  }

  // ---- cell update epilogue ----
  const float* bias = dir ? b_b : b_f;
  const int m = mt*32 + wm*16 + lr;            // dir-local m in [0,512)
  const float bi = bias[m], bfv = bias[H_+m], bg = bias[2*H_+m], bo = bias[3*H_+m];
  float* cbp = cb + (size_t)dir*N_*H_;
  u16* ho = hbf_out + (size_t)dir*N_*H_;
  #pragma unroll
  for(int nf=0; nf<4; ++nf){
    #pragma unroll
    for(int r=0; r<4; ++r){
      const int n = n0 + wn*64 + nf*16 + lh*4 + r;
      float gi = acc[nf][0][r] + bi;
      float gf = acc[nf][1][r] + bfv;
      float gc = acc[nf][2][r] + bg;
      float go = acc[nf][3][r] + bo;
      float c_old = cbp[(size_t)n*H_ + m];
      float c2 = sigm(gf)*c_old + sigm(gi)*tanhf(gc);
      float h2 = sigm(go)*tanhf(c2);
      cbp[(size_t)n*H_ + m] = c2;
      if(t == TW_-1) featsbf[(size_t)n*E_ + dir*H_ + m] = f2bf(h2);
      else           ho[(size_t)n*H_ + m] = f2bf(h2);
    }
  }
}

// ===========================================================================
// q = feats @ W_att  (one-time, bf16 MFMA, fp32 out)  [unchanged, verified]
// ===========================================================================
__global__ __launch_bounds__(256) void k_qgemm(const u16* __restrict__ featsbf,
                                               const u16* __restrict__ WattT,
                                               float* __restrict__ q)
{
  const int n0 = blockIdx.x*64, j0 = blockIdx.y*64;
  __shared__ __align__(16) u16 As[64*40];
  __shared__ __align__(16) u16 Bs[64*40];
  const int tid = threadIdx.x;
  const int w = tid>>6, l = tid&63, lr = l&15, lk = (l>>4)*8;
  const int arow = tid>>2, ak8 = (tid&3)*8;

  f32x4 acc[4];
  #pragma unroll
  for(int i=0;i<4;i++) acc[i] = (f32x4){0.f,0.f,0.f,0.f};

  for(int kc=0; kc<32; ++kc){
    *(s16x8*)&As[arow*40 + ak8] = *(const s16x8*)&featsbf[(size_t)(n0+arow)*E_ + kc*32 + ak8];
    *(s16x8*)&Bs[arow*40 + ak8] = *(const s16x8*)&WattT[(size_t)(j0+arow)*E_ + kc*32 + ak8];
    __syncthreads();
    s16x8 av = *(const s16x8*)&As[(w*16 + lr)*40 + lk];
    #pragma unroll
    for(int mf=0; mf<4; ++mf){
      s16x8 bv = *(const s16x8*)&Bs[(mf*16 + lr)*40 + lk];
      acc[mf] = __builtin_amdgcn_mfma_f32_16x16x32_bf16(av, bv, acc[mf], 0,0,0);
    }
    __syncthreads();
  }
  #pragma unroll
  for(int mf=0; mf<4; ++mf)
    #pragma unroll
    for(int r=0; r<4; ++r){
      int n = n0 + w*16 + (l>>4)*4 + r;
      q[(size_t)n*E_ + j0 + mf*16 + lr] = acc[mf][r];
    }
}

// ===========================================================================
// Phase 2 building blocks
// ===========================================================================
struct GArg2 {
  const u16* xA; const u16* xB;
  long ldA; long ldB;
  const u16* W; int K;
};

// M=32 split-K partial GEMM: 32n x 128c, 4 waves, dbuf, gload_lds for W.
// LDS layout in smem: Xs0[32*40], Xs1[32*40], Ws0[128*32], Ws1[128*32]
__device__ __forceinline__ void gemm32v2(const GArg2 a, int R, int xt, int ks,
                                         int KS, int z, float* __restrict__ part,
                                         char* smem)
{
  u16* Xs0 = (u16*)smem;
  u16* Xs1 = Xs0 + 32*40;
  u16* Ws0 = Xs1 + 32*40;
  u16* Ws1 = Ws0 + 128*32;
  const int Kc = a.K / KS;
  const int nch = Kc >> 5;
  const int kb0 = ks * Kc;
  const int tid = threadIdx.x;
  const int w = tid>>6, l = tid&63, lr = l&15, lh = l>>4;

  f32x4 a00={0,0,0,0}, a01={0,0,0,0}, a10={0,0,0,0}, a11={0,0,0,0};

  auto issueW = [&](int c, u16* Wb){
    const int kb = kb0 + c*32;
    #pragma unroll
    for(int c2=0;c2<2;++c2){
      const int cc = w*2 + c2;
      const char* g = (const char*)(a.W + (size_t)(xt*128 + cc*16 + (l>>2))*a.K + kb) + (l&3)*16;
      g2lds16(g, (char*)Wb + cc*1024);
    }
  };
  auto loadX = [&](int c, short4* xr){
    const int kb = kb0 + c*32;
    const int row = tid>>3, k4 = (tid&7)*4;
    short4 xv = *(const short4*)&a.xA[(size_t)row*a.ldA + kb + k4];
    if(a.xB){
      short4 yv = *(const short4*)&a.xB[(size_t)row*a.ldB + kb + k4];
      xv.x = (short)f2bf(bf2f((u16)xv.x)+bf2f((u16)yv.x));
      xv.y = (short)f2bf(bf2f((u16)xv.y)+bf2f((u16)yv.y));
      xv.z = (short)f2bf(bf2f((u16)xv.z)+bf2f((u16)yv.z));
      xv.w = (short)f2bf(bf2f((u16)xv.w)+bf2f((u16)yv.w));
    }
    *xr = xv;
  };
  auto writeX = [&](short4 xv, u16* Xb){
    *(short4*)&Xb[(tid>>3)*40 + (tid&7)*4] = xv;
  };

  short4 xr;
  issueW(0, Ws0); loadX(0, &xr); writeX(xr, Xs0);
  __syncthreads();
  for(int c=0;c<nch;++c){
    u16* Xc = (c&1)?Xs1:Xs0; u16* Wc = (c&1)?Ws1:Ws0;
    u16* Xn = (c&1)?Xs0:Xs1; u16* Wn = (c&1)?Ws0:Ws1;
    const bool pre = (c+1 < nch);
    if(pre){ issueW(c+1, Wn); loadX(c+1, &xr); }
    s16x8 av0 = *(const s16x8*)&Xc[lr*40 + lh*8];
    s16x8 av1 = *(const s16x8*)&Xc[(16+lr)*40 + lh*8];
    s16x8 bv0 = *(const s16x8*)&Wc[(w*32 + lr)*32 + lh*8];
    s16x8 bv1 = *(const s16x8*)&Wc[(w*32 + 16 + lr)*32 + lh*8];
    a00 = __builtin_amdgcn_mfma_f32_16x16x32_bf16(av0, bv0, a00, 0,0,0);
    a01 = __builtin_amdgcn_mfma_f32_16x16x32_bf16(av0, bv1, a01, 0,0,0);
    a10 = __builtin_amdgcn_mfma_f32_16x16x32_bf16(av1, bv0, a10, 0,0,0);
    a11 = __builtin_amdgcn_mfma_f32_16x16x32_bf16(av1, bv1, a11, 0,0,0);
    if(pre) writeX(xr, Xn);
    __syncthreads();
  }
  float* dst = part + (size_t)((z*KS + ks)*B_)*R + xt*128 + w*32;
  f32x4 accs[2][2] = {{a00,a01},{a10,a11}};
  #pragma unroll
  for(int nf=0; nf<2; ++nf)
    #pragma unroll
    for(int mf=0; mf<2; ++mf)
      #pragma unroll
      for(int r=0; r<4; ++r){
        int n = nf*16 + lh*4 + r;
        dst[(size_t)n*R + mf*16 + lr] = accs[nf][mf][r];
      }
}

// attention body: one block per b (256 thr). q row n = b*T_ + i
__device__ __forceinline__ void att_body(const float* __restrict__ q,
                                         const u16* __restrict__ histbf,
                                         const u16* __restrict__ featsbf,
                                         u16* __restrict__ xcbf,
                                         int i, int b, char* smem)
{
  float* qs = (float*)smem;      // 1024
  float* sc = qs + E_;           // 64
  const int tid = threadIdx.x;
  *(float4*)&qs[tid*4] = *(const float4*)&q[((size_t)b*T_ + i)*E_ + tid*4];
  __syncthreads();
  const int wv = tid>>6, ln = tid&63;
  for(int L = wv; L <= i; L += 4){
    const u16* hl = histbf + ((size_t)L*B_ + b)*E_;
    float s = 0.f;
    s16x8 h0 = *(const s16x8*)&hl[ln*16];
    s16x8 h1 = *(const s16x8*)&hl[ln*16 + 8];
    #pragma unroll
    for(int j=0;j<8;j++){
      s += qs[ln*16 + j]     * bf2f((u16)h0[j]);
      s += qs[ln*16 + 8 + j] * bf2f((u16)h1[j]);
    }
    #pragma unroll
    for(int off=32; off; off>>=1) s += __shfl_down(s, off);
    if(ln == 0) sc[L] = s;
  }
  __syncthreads();
  if(tid < 64){
    float v  = (tid <= i) ? sc[tid] : -INFINITY;
    float mx = v;
    #pragma unroll
    for(int off=32; off; off>>=1) mx = fmaxf(mx, __shfl_xor(mx, off));
    float ex = (tid <= i) ? expf(v - mx) : 0.f;
    float sm = ex;
    #pragma unroll
    for(int off=32; off; off>>=1) sm += __shfl_xor(sm, off);
    sc[tid] = ex / sm;
  }
  __syncthreads();
  const int e4 = tid*4;
  float c0=0.f, c1=0.f, c2=0.f, c3=0.f;
  for(int L=0; L<=i; ++L){
    float wl = sc[L];
    short4 hv = *(const short4*)&histbf[((size_t)L*B_ + b)*E_ + e4];
    c0 += wl*bf2f((u16)hv.x);
    c1 += wl*bf2f((u16)hv.y);
    c2 += wl*bf2f((u16)hv.z);
    c3 += wl*bf2f((u16)hv.w);
  }
  const u16* xi = featsbf + ((size_t)b*T_ + i)*E_ + e4;
  xcbf[(size_t)b*E_ + e4 + 0] = f2bf(bf2f(xi[0]) + c0);
  xcbf[(size_t)b*E_ + e4 + 1] = f2bf(bf2f(xi[1]) + c1);
  xcbf[(size_t)b*E_ + e4 + 2] = f2bf(bf2f(xi[2]) + c2);
  xcbf[(size_t)b*E_ + e4 + 3] = f2bf(bf2f(xi[3]) + c3);
}

// GRU combine: reduce split-K partials + nonlinearity; fp32 master state.
__device__ __forceinline__ void gru_comb(const float* __restrict__ part, int R, int J, int KS,
                                         const float* __restrict__ bih, const float* __restrict__ bhh,
                                         const float* __restrict__ hprev_f,
                                         float* __restrict__ dst_f,
                                         u16* __restrict__ dstbf,
                                         float* __restrict__ dst_seq, int idx)
{
  const int b = idx / J, e = idx - b*J;
  float ir=0.f, iz=0.f, in_=0.f, hr=0.f, hz=0.f, hn=0.f;
  for(int ks=0; ks<KS; ++ks){
    const float* p0 = part + (size_t)(ks*B_ + b)*R;
    const float* p1 = part + (size_t)((KS+ks)*B_ + b)*R;
    ir += p0[e]; iz += p0[J+e]; in_ += p0[2*J+e];
    hr += p1[e]; hz += p1[J+e]; hn  += p1[2*J+e];
  }
  ir += bih[e]; iz += bih[J+e]; in_ += bih[2*J+e];
  hr += bhh[e]; hz += bhh[J+e]; hn  += bhh[2*J+e];
  const float r = sigm(ir + hr);
  const float z = sigm(iz + hz);
  const float n = tanhf(in_ + r*hn);
  const float hp = hprev_f[(size_t)b*J + e];
  const float h2 = (1.f - z)*n + z*hp;
  dst_f[(size_t)b*J + e] = h2;
  dstbf[(size_t)b*J + e] = f2bf(h2);
  if(dst_seq) dst_seq[(size_t)b*J + e] = h2;
}

// A(i): g-gemm(i) [384] | e-gemm(i-1) [192] | att(i) [32]   grid 608
__global__ __launch_bounds__(256) void k_A(GArg2 g0, GArg2 g1, GArg2 e0, GArg2 e1,
    float* __restrict__ part_g, float* __restrict__ part_e,
    const float* __restrict__ q, const u16* __restrict__ histbf,
    const u16* __restrict__ featsbf, u16* __restrict__ xcbf, int i)
{
  __shared__ __align__(16) char smem[21504];
  const int x = blockIdx.x;
  if(x < 384){
    if(i >= T_) return;
    const int xt = x % 24, ks = (x/24) & 7, z = x/192;
    gemm32v2(z ? g1 : g0, 3*E_, xt, ks, 8, z, part_g, smem);
  } else if(x < 576){
    if(i < 1) return;
    const int ix = x-384, xt = ix % 12, ks = (ix/12) & 7, z = ix/96;
    gemm32v2(z ? e1 : e0, 3*HH_, xt, ks, 8, z, part_e, smem);
  } else {
    if(i >= T_) return;
    att_body(q, histbf, featsbf, xcbf, i, x-576, smem);
  }
}

// B(i): g-comb(i) [128] | p-gemm(i) [384] | e-comb(i-1) [64]   grid 576
__global__ __launch_bounds__(256) void k_B(GArg2 p0, GArg2 p1,
    const float* __restrict__ part_g, const float* __restrict__ part_e,
    const float* __restrict__ g_bih, const float* __restrict__ g_bhh,
    const float* __restrict__ e_bih, const float* __restrict__ e_bhh,
    const float* __restrict__ gf_prev, float* __restrict__ gf_next,
    u16* __restrict__ histbf,
    float* __restrict__ emof, u16* __restrict__ emobf,
    float* __restrict__ emo_seq, float* __restrict__ part_p, int i)
{
  __shared__ __align__(16) char smem[21504];
  const int x = blockIdx.x;
  if(x < 128){
    if(i >= T_) return;
    gru_comb(part_g, 3*E_, E_, 8, g_bih, g_bhh,
             gf_prev, gf_next, histbf + (size_t)(i+1)*B_*E_, nullptr,
             x*256 + (int)threadIdx.x);
  } else if(x < 512){
    if(i >= T_) return;
    const int ix = x-128, xt = ix % 24, ks = (ix/24) & 7, z = ix/192;
    gemm32v2(z ? p1 : p0, 3*E_, xt, ks, 8, z, part_p, smem);
  } else {
    if(i < 1) return;
    gru_comb(part_e, 3*HH_, HH_, 8, e_bih, e_bhh,
             emof, emof, emobf, emo_seq + (size_t)(i-1)*B_*HH_,
             (x-512)*256 + (int)threadIdx.x);
  }
}

// C(i): p-comb(i)   grid 128
__global__ __launch_bounds__(256) void k_C(const float* __restrict__ part_p,
    const float* __restrict__ p_bih, const float* __restrict__ p_bhh,
    float* __restrict__ partyf_p, u16* __restrict__ partybf_p)
{
  const int idx = blockIdx.x*256 + threadIdx.x;
  gru_comb(part_p, 3*E_, E_, 8, p_bih, p_bhh, partyf_p, partyf_p, partybf_p, nullptr, idx);
}

// classifier
__global__ __launch_bounds__(256) void classify(const float* __restrict__ emo_seq,
    const float* __restrict__ clsW, const float* __restrict__ clsb, float* __restrict__ out)
{
  const int idx = blockIdx.x*256 + threadIdx.x;
  if(idx >= B_*T_*C_) return;
  const int c = idx % C_;
  const int bt = idx / C_;
  const int t = bt % T_, b = bt / T_;
  const float* e = emo_seq + (size_t)(t*B_ + b)*HH_;
  const float* w = clsW + (size_t)c*HH_;
  float s = clsb[c];
  for(int h=0; h<HH_; ++h) s += e[h]*w[h];
  out[idx] = s;
}

// ===========================================================================
extern "C" void kernel_launch(void* const* d_in, const int* in_sizes, int n_in,
                              void* d_out, int out_size, void* d_ws, size_t ws_size,
                              hipStream_t stream)
{
  const float* input  = (const float*)d_in[0];
  const float* Wih_f  = (const float*)d_in[1];
  const float* Whh_f  = (const float*)d_in[2];
  const float* b_f    = (const float*)d_in[3];
  const float* Wih_b  = (const float*)d_in[4];
  const float* Whh_b  = (const float*)d_in[5];
  const float* b_b    = (const float*)d_in[6];
  const float* W_att  = (const float*)d_in[7];
  const float* g_Wih  = (const float*)d_in[8];
  const float* g_Whh  = (const float*)d_in[9];
  const float* g_bih  = (const float*)d_in[10];
  const float* g_bhh  = (const float*)d_in[11];
  const float* p_Wih  = (const float*)d_in[12];
  const float* p_Whh  = (const float*)d_in[13];
  const float* p_bih  = (const float*)d_in[14];
  const float* p_bhh  = (const float*)d_in[15];
  const float* e_Wih  = (const float*)d_in[16];
  const float* e_Whh  = (const float*)d_in[17];
  const float* e_bih  = (const float*)d_in[18];
  const float* e_bhh  = (const float*)d_in[19];
  const float* cls_W  = (const float*)d_in[20];
  const float* cls_b  = (const float*)d_in[21];

  // ---- workspace layout ----
  char* base = (char*)d_ws;
  size_t off = 0;
  auto alloc = [&](size_t bytes)->char*{
    char* p = base + off; off += (bytes + 255) & ~(size_t)255; return p;
  };
  u16*   Wpack2  = (u16*)alloc((size_t)4096*832*2);          // 6.8 MB
  u16*   hbfA    = (u16*)alloc((size_t)2*N_*H_*2);           // 4.2 MB (phase1 only)
  u16*   hbfB    = (u16*)alloc((size_t)2*N_*H_*2);           // 4.2 MB (phase1 only)
  float* cb      = (float*)alloc((size_t)2*N_*H_*4);         // 8.4 MB (phase1 only)
  u16*   featsbf = (u16*)alloc((size_t)N_*E_*2);
  float* q       = (float*)alloc((size_t)N_*E_*4);
  u16*   WattT   = (u16*)alloc((size_t)E_*E_*2);
  u16*   gWih    = (u16*)alloc((size_t)3*E_*E_*2);
  u16*   gWhh    = (u16*)alloc((size_t)3*E_*E_*2);
  u16*   pWih    = (u16*)alloc((size_t)3*E_*E_*2);
  u16*   pWhh    = (u16*)alloc((size_t)3*E_*E_*2);
  u16*   eWih    = (u16*)alloc((size_t)3*HH_*E_*2);
  u16*   eWhh    = (u16*)alloc((size_t)3*HH_*HH_*2);
  u16*   histbf  = (u16*)alloc((size_t)(T_+1)*B_*E_*2);
  float* gfbuf   = (float*)alloc((size_t)2*B_*E_*4);
  float* partyf  = (float*)alloc((size_t)2*B_*E_*4);
  u16*   partybf = (u16*)alloc((size_t)2*B_*E_*2);
  float* emof    = (float*)alloc((size_t)B_*HH_*4);
  u16*   emobf   = (u16*)alloc((size_t)B_*HH_*2);
  float* emo_seq = (float*)alloc((size_t)T_*B_*HH_*4);
  u16*   xcbf    = (u16*)alloc((size_t)B_*E_*2);
  float* part_e  = (float*)alloc((size_t)16*B_*3*HH_*4);     // 3.1 MB
  // phase-2 partials alias phase-1-only buffers (dead after lstm loop):
  float* part_g  = (float*)cb;                               // 6.3 <= 8.4 MB
  float* part_p  = (float*)hbfA;                             // 6.3 <= 8.4 MB (A+B region)

  // ---- zero-init recurrent state ----
  hipMemsetAsync(hbfA,    0, (size_t)2*N_*H_*2, stream);
  hipMemsetAsync(cb,      0, (size_t)2*N_*H_*4, stream);
  hipMemsetAsync(histbf,  0, (size_t)B_*E_*2, stream);        // slice 0
  hipMemsetAsync(gfbuf,   0, (size_t)B_*E_*4, stream);        // slice 0
  hipMemsetAsync(partyf,  0, (size_t)2*B_*E_*4, stream);
  hipMemsetAsync(partybf, 0, (size_t)2*B_*E_*2, stream);
  hipMemsetAsync(emof,    0, (size_t)B_*HH_*4, stream);
  hipMemsetAsync(emobf,   0, (size_t)B_*HH_*2, stream);

  // ---- pre-pass conversions ----
  k_pack_lstm<<<dim3(((size_t)4096*832+255)/256), 256, 0, stream>>>(Wih_f, Whh_f, Wih_b, Whh_b, Wpack2);
  k_f2bf<<<dim3((3*E_*E_+255)/256), 256, 0, stream>>>(g_Wih, gWih, 3*E_*E_);
  k_f2bf<<<dim3((3*E_*E_+255)/256), 256, 0, stream>>>(g_Whh, gWhh, 3*E_*E_);
  k_f2bf<<<dim3((3*E_*E_+255)/256), 256, 0, stream>>>(p_Wih, pWih, 3*E_*E_);
  k_f2bf<<<dim3((3*E_*E_+255)/256), 256, 0, stream>>>(p_Whh, pWhh, 3*E_*E_);
  k_f2bf<<<dim3((3*HH_*E_+255)/256), 256, 0, stream>>>(e_Wih, eWih, 3*HH_*E_);
  k_f2bf<<<dim3((3*HH_*HH_+255)/256), 256, 0, stream>>>(e_Whh, eWhh, 3*HH_*HH_);
  k_wattT<<<dim3((E_*E_+255)/256), 256, 0, stream>>>(W_att, WattT);

  // ---- Phase 1: BiLSTM ----
  for(int t=0; t<TW_; ++t){
    u16* hin  = (t & 1) ? hbfB : hbfA;
    u16* hout = (t & 1) ? hbfA : hbfB;
    lstm2<<<dim3(32, 16), 256, 0, stream>>>(input, Wpack2, b_f, b_b,
                                            hin, hout, cb, featsbf, t);
  }

  // ---- q = feats @ W_att ----
  k_qgemm<<<dim3(32, 16), 256, 0, stream>>>(featsbf, WattT, q);

  // ---- Phase 2: 3 launches/step ----
  for(int i=0; i<=T_; ++i){
    const int p  = i & 1;
    const int pe = (i-1) & 1;
    GArg2 ga0{ featsbf + (size_t)i*E_, partybf + (size_t)p*B_*E_, (long)T_*E_, (long)E_, gWih, E_ };
    GArg2 ga1{ histbf + (size_t)i*B_*E_, nullptr, (long)E_, 0, gWhh, E_ };
    GArg2 ea0{ partybf + (size_t)pe*B_*E_, nullptr, (long)E_, 0, eWih, E_ };
    GArg2 ea1{ emobf, nullptr, (long)HH_, 0, eWhh, HH_ };
    k_A<<<dim3(608), 256, 0, stream>>>(ga0, ga1, ea0, ea1, part_g, part_e,
                                       q, histbf, featsbf, xcbf, i);
    GArg2 pa0{ xcbf, nullptr, (long)E_, 0, pWih, E_ };
    GArg2 pa1{ partybf + (size_t)p*B_*E_, nullptr, (long)E_, 0, pWhh, E_ };
    k_B<<<dim3(576), 256, 0, stream>>>(pa0, pa1, part_g, part_e,
                                       g_bih, g_bhh, e_bih, e_bhh,
                                       gfbuf + (size_t)(i&1)*B_*E_,
                                       gfbuf + (size_t)((i+1)&1)*B_*E_,
                                       histbf, emof, emobf, emo_seq, part_p, i);
    if(i < T_){
      k_C<<<dim3(128), 256, 0, stream>>>(part_p, p_bih, p_bhh,
                                         partyf + (size_t)p*B_*E_,
                                         partybf + (size_t)p*B_*E_);
    }
  }

  // ---- classifier ----
  classify<<<dim3((B_*T_*C_+255)/256), 256, 0, stream>>>(emo_seq, cls_W, cls_b, (float*)d_out);
}